// Round 1
// 614.356 us; speedup vs baseline: 1.0343x; 1.0343x over previous
//
#include <hip/hip_runtime.h>
#include <stdint.h>

typedef __bf16 bf16;
typedef bf16 bf16x8 __attribute__((ext_vector_type(8)));
typedef float f32x4 __attribute__((ext_vector_type(4)));

#define B_ROWS   65536
#define K1       784
#define FLAG_CAP 262144

// workspace layout (bytes)
#define CNT_OFF  0          // 4 B flag counter
#define LIST_OFF 4096       // 1 MB flag list
#define S1F_OFF  1052672    // 409600 B fragment-tiled sign(w1), zero-padded K->800
#define W2P_OFF  1462272    // 128x8 u32 packed sign(w2)
#define W3P_OFF  1466368    // 32x4 u32 packed sign(w3)
#define W4P_OFF  1466880    // 16 u32 packed sign(w4)
#define H1P_OFF  1470464    // 65536x8 u32 packed h1 signs -> 2 MB

#define AS1C(p) ((const __attribute__((address_space(1))) void*)(p))
#define AS3(p)  ((__attribute__((address_space(3))) void*)(p))

// ---------------- prep: binarize/pack weights, zero flag counter ----------------
// s1f fragment-tiled layout: element e = (((step*16 + ntile)*64 + lane)*8 + j)
//   holds sign(w1)[ntile*16 + (lane&15)][step*32 + (lane>>4)*8 + j], 0 for k>=784.
// gemm1 then loads B-fragments as fully-coalesced 16 B/lane dwordx4 from L2.
__global__ __launch_bounds__(256) void prep_kernel(
    const float* __restrict__ w1, const float* __restrict__ w2,
    const float* __restrict__ w3, const float* __restrict__ w4,
    bf16* __restrict__ s1f, uint32_t* __restrict__ w2p,
    uint32_t* __restrict__ w3p, uint32_t* __restrict__ w4p,
    uint32_t* __restrict__ cnt) {
  int gid = blockIdx.x * 256 + threadIdx.x;   // 0..204799 == 25*16*64*8
  if (gid == 0) *cnt = 0u;
  {
    int j = gid & 7, l = (gid >> 3) & 63, t = (gid >> 9) & 15, s = gid >> 13;
    int fr = l & 15, fg = l >> 4;
    int n = t * 16 + fr;
    int k = s * 32 + fg * 8 + j;
    bf16 v = (bf16)0.0f;
    if (k < K1) v = (w1[n * K1 + k] >= 0.0f) ? (bf16)1.0f : (bf16)-1.0f;
    s1f[gid] = v;
  }
  if (gid < 1024) {                       // w2: 128 rows x 8 words
    int j = gid >> 3, w = gid & 7;
    uint32_t bits = 0;
    for (int i = 0; i < 32; ++i)
      bits |= (w2[j * 256 + w * 32 + i] >= 0.0f ? 1u : 0u) << i;
    w2p[gid] = bits;
  }
  if (gid < 128) {                        // w3: 32 rows x 4 words
    int j = gid >> 2, w = gid & 3;
    uint32_t bits = 0;
    for (int i = 0; i < 32; ++i)
      bits |= (w3[j * 128 + w * 32 + i] >= 0.0f ? 1u : 0u) << i;
    w3p[gid] = bits;
  }
  if (gid < 16) {                         // w4: 10 rows x 1 word (pad to 16)
    uint32_t bits = 0;
    if (gid < 10)
      for (int i = 0; i < 32; ++i)
        bits |= (w4[gid * 32 + i] >= 0.0f ? 1u : 0u) << i;
    w4p[gid] = bits;
  }
}

// ---------------- layer 1: x @ sign(w1)^T via split-bf16 MFMA ----------------
// 128x128 C-tile per block (grid 1024, XCD-bijective swizzle, col-fast pairing),
// 4 waves (2x2), wave tile 64x64 -> acc = 64 regs (3 waves/SIMD on unified RF).
// x staged raw-fp32 into LDS via global_load_lds (16 B, no VGPR round-trip),
// XOR-swizzled (chunk p holds global chunk p^(row&7)) so fragment ds_read_b128
// spreads uniformly over all 32 banks. hi/lo bf16 split done at read time —
// op-for-op identical numerics to the verified previous kernel.
// B-fragments come straight from L2 (s1f), register double-buffered. One
// barrier per K-step; async stage for next step is in flight across the MFMAs.
__global__ __launch_bounds__(256, 3) void gemm1_kernel(
    const float* __restrict__ x, const bf16* __restrict__ s1f,
    uint8_t* __restrict__ h1b, uint32_t* __restrict__ cnt,
    uint32_t* __restrict__ list) {
  __shared__ __align__(16) float Xs[2][4096];   // 2 x 16 KB raw fp32 x tiles

  const int tid = threadIdx.x;
  const int lane = tid & 63;
  const int wid = tid >> 6;
  const int wm = wid & 1, wn = wid >> 1;
  const int fr = lane & 15, fg = lane >> 4;

  // XCD-bijective swizzle (1024 % 8 == 0), col-fast: blocks 2i,2i+1 share rows
  const int orig = blockIdx.x;
  const int bid = (orig & 7) * 128 + (orig >> 3);
  const int rb = bid >> 1, cb = bid & 1;

  f32x4 acc[4][4];
#pragma unroll
  for (int i = 0; i < 4; ++i)
#pragma unroll
    for (int j = 0; j < 4; ++j) acc[i][j] = (f32x4){0.f, 0.f, 0.f, 0.f};

  // x staging: round it stages rows it*32..+31; thread covers (row = it*32 + tid>>3,
  // chunk-slot p = tid&7). Linear LDS dest byte = it*4096 + tid*16 (= wave base +
  // lane*16). Global source chunk d = p ^ (row&7)  (inverse swizzle, rule 21).
  const int srow = tid >> 3, sp = tid & 7;
  const int sd = sp ^ (srow & 7);
  const float* xg = x + ((size_t)rb * 128 + srow) * K1 + sd * 4;
  char* ldsbase = (char*)&Xs[0][0];

#define STAGE_ASYNC(buf_, t_)                                                  \
  {                                                                            \
    _Pragma("unroll") for (int it = 0; it < 4; ++it)                           \
        __builtin_amdgcn_global_load_lds(                                      \
            AS1C(xg + (size_t)it * 32 * K1 + (size_t)(t_) * 32),               \
            AS3(ldsbase + (buf_) * 16384 + it * 4096 + wid * 1024), 16, 0, 0); \
  }

  // k-tail (step 24, k=768..799): predicated register path, same linear+swizzle
#define STAGE_TAIL(buf_)                                                       \
  {                                                                            \
    _Pragma("unroll") for (int it = 0; it < 4; ++it) {                         \
      float4 v = make_float4(0.f, 0.f, 0.f, 0.f);                              \
      if (sd < 4) v = *(const float4*)(xg + (size_t)it * 32 * K1 + 768);       \
      *(float4*)(ldsbase + (buf_) * 16384 + it * 4096 + tid * 16) = v;         \
    }                                                                          \
  }

  const bf16* bbase = s1f + ((size_t)(cb * 8 + wn * 4) * 64 + lane) * 8;
#define LOAD_B(dst_, t_)                                                       \
  {                                                                            \
    _Pragma("unroll") for (int j = 0; j < 4; ++j)                              \
        dst_[j] = *(const bf16x8*)(bbase + ((size_t)(t_) * 16 + j) * 512);     \
  }

  const int arow = wm * 64 + fr;                 // + i*16
  const int asw0 = ((2 * fg) ^ (fr & 7)) * 16;   // swizzled 16B-chunk offsets
  const int asw1 = ((2 * fg + 1) ^ (fr & 7)) * 16;

  bf16x8 bcur[4], bnxt[4];
  STAGE_ASYNC(0, 0);
  LOAD_B(bcur, 0);
  __syncthreads();

  for (int t = 0; t < 25; ++t) {
    const int cur = t & 1;
    if (t < 23) { STAGE_ASYNC(cur ^ 1, t + 1); }
    else if (t == 23) { STAGE_TAIL(cur ^ 1); }
    if (t < 24) { LOAD_B(bnxt, t + 1); }

    const char* xb = ldsbase + cur * 16384;
#pragma unroll
    for (int i = 0; i < 4; ++i) {
      const char* rbase = xb + (arow + i * 16) * 128;
      f32x4 a0 = *(const f32x4*)(rbase + asw0);   // floats fg*8..fg*8+3
      f32x4 a1 = *(const f32x4*)(rbase + asw1);   // floats fg*8+4..fg*8+7
      bf16 h0 = (bf16)a0[0], h1 = (bf16)a0[1], h2 = (bf16)a0[2], h3 = (bf16)a0[3];
      bf16 h4 = (bf16)a1[0], h5 = (bf16)a1[1], h6 = (bf16)a1[2], h7 = (bf16)a1[3];
      bf16 l0 = (bf16)(a0[0] - (float)h0), l1 = (bf16)(a0[1] - (float)h1);
      bf16 l2 = (bf16)(a0[2] - (float)h2), l3 = (bf16)(a0[3] - (float)h3);
      bf16 l4 = (bf16)(a1[0] - (float)h4), l5 = (bf16)(a1[1] - (float)h5);
      bf16 l6 = (bf16)(a1[2] - (float)h6), l7 = (bf16)(a1[3] - (float)h7);
      bf16x8 ah = (bf16x8){h0, h1, h2, h3, h4, h5, h6, h7};
      bf16x8 al = (bf16x8){l0, l1, l2, l3, l4, l5, l6, l7};
#pragma unroll
      for (int j = 0; j < 4; ++j) {
        acc[i][j] = __builtin_amdgcn_mfma_f32_16x16x32_bf16(ah, bcur[j], acc[i][j], 0, 0, 0);
        acc[i][j] = __builtin_amdgcn_mfma_f32_16x16x32_bf16(al, bcur[j], acc[i][j], 0, 0, 0);
      }
    }
    if (t < 24) {
      __syncthreads();   // drains stage(t+1) + B prefetch; tile t+1 ready
#pragma unroll
      for (int j = 0; j < 4; ++j) bcur[j] = bnxt[j];
    }
  }

  // epilogue: pack signs via ballot; flag |v|<0.05 (ballot-aggregated atomics).
  // C/D layout: col = lane&15, row = (lane>>4)*4 + reg.
  const int m0 = rb * 128 + wm * 64;
  const int n0 = cb * 128 + wn * 64;
#pragma unroll
  for (int i = 0; i < 4; ++i) {
#pragma unroll
    for (int r = 0; r < 4; ++r) {
      unsigned long long sb[4];
#pragma unroll
      for (int j = 0; j < 4; ++j) {
        float v = acc[i][j][r];
        sb[j] = __ballot(v >= 0.0f);
        unsigned long long fb = __ballot(__builtin_fabsf(v) < 0.05f);
        if (fb) {
          int leader = __ffsll(fb) - 1;
          uint32_t base = 0;
          if (lane == leader) base = atomicAdd(cnt, (uint32_t)__popcll(fb));
          base = __shfl(base, leader);
          if (__builtin_fabsf(v) < 0.05f) {
            uint32_t pos = base + (uint32_t)__popcll(fb & ((1ull << lane) - 1ull));
            if (pos < FLAG_CAP)
              list[pos] = ((uint32_t)(m0 + i * 16 + fg * 4 + r) << 8) |
                          (uint32_t)(n0 + j * 16 + fr);
          }
        }
      }
      if (fr == 0) {  // lanes 0,16,32,48 each write one row's 64-bit slice
        int m = m0 + i * 16 + fg * 4 + r;
        int sh = fg * 16;
        uint32_t u0 = (uint32_t)((sb[0] >> sh) & 0xFFFF) |
                      ((uint32_t)((sb[1] >> sh) & 0xFFFF) << 16);
        uint32_t u1 = (uint32_t)((sb[2] >> sh) & 0xFFFF) |
                      ((uint32_t)((sb[3] >> sh) & 0xFFFF) << 16);
        *(uint2*)(h1b + (size_t)m * 32 + (cb * 16 + wn * 8)) = make_uint2(u0, u1);
      }
    }
  }
}

// ---------------- cleanup: recompute flagged dots EXACTLY as the fp32 reference ----------------
// VERIFIED (absmax=0): reference = BLIS/AOCL-style sgemm, KC=512, full panels
// then remainder; one fp32 accumulator per C element, ascending k in panel;
// C = fl( seq[0,512) + seq[512,784) ).
__global__ __launch_bounds__(256) void cleanup_kernel(
    const float* __restrict__ x, const float* __restrict__ w1,
    uint32_t* __restrict__ h1p, const uint32_t* __restrict__ cnt,
    const uint32_t* __restrict__ list) {
  uint32_t n = *cnt;
  if (n > FLAG_CAP) n = FLAG_CAP;
  for (uint32_t idx = blockIdx.x * 256 + threadIdx.x; idx < n; idx += 65536) {
    uint32_t e = list[idx];
    uint32_t col = e & 255u, b = e >> 8;
    const float4* xr4 = (const float4*)(x + (size_t)b * K1);
    const float4* wr4 = (const float4*)(w1 + (size_t)col * K1);
    float t1 = 0.0f, t2 = 0.0f;
    for (int k4 = 0; k4 < 128; ++k4) {          // k in [0,512)
      float4 xv = xr4[k4], wv = wr4[k4];
      t1 += (wv.x >= 0.f) ? xv.x : -xv.x;
      t1 += (wv.y >= 0.f) ? xv.y : -xv.y;
      t1 += (wv.z >= 0.f) ? xv.z : -xv.z;
      t1 += (wv.w >= 0.f) ? xv.w : -xv.w;
    }
    for (int k4 = 128; k4 < 196; ++k4) {        // k in [512,784)
      float4 xv = xr4[k4], wv = wr4[k4];
      t2 += (wv.x >= 0.f) ? xv.x : -xv.x;
      t2 += (wv.y >= 0.f) ? xv.y : -xv.y;
      t2 += (wv.z >= 0.f) ? xv.z : -xv.z;
      t2 += (wv.w >= 0.f) ? xv.w : -xv.w;
    }
    float s = t1 + t2;   // single K-panel join at 512 (BLIS KC)
    uint32_t word = b * 8u + (col >> 5);
    uint32_t mask = 1u << (col & 31u);
    if (s >= 0.0f) atomicOr(&h1p[word], mask);
    else           atomicAnd(&h1p[word], ~mask);
  }
}

// ---------------- layers 2-4: xor/popcount, one thread per batch row ----------------
__global__ __launch_bounds__(256) void layer234_kernel(
    const uint32_t* __restrict__ h1p, const uint32_t* __restrict__ w2p,
    const uint32_t* __restrict__ w3p, const uint32_t* __restrict__ w4p,
    float* __restrict__ out) {
  __shared__ __align__(16) uint32_t lw[1168];  // [0,1024) w2p, [1024,1152) w3p, [1152,1168) w4p
  for (int i = threadIdx.x; i < 1168; i += 256) {
    uint32_t v;
    if (i < 1024) v = w2p[i];
    else if (i < 1152) v = w3p[i - 1024];
    else v = w4p[i - 1152];
    lw[i] = v;
  }
  __syncthreads();
  int b = blockIdx.x * 256 + threadIdx.x;
  const uint4* hp = (const uint4*)h1p;
  uint4 a0 = hp[(size_t)b * 2], a1 = hp[(size_t)b * 2 + 1];

  uint32_t h2w[4] = {0u, 0u, 0u, 0u};
#pragma unroll 4
  for (int j = 0; j < 128; ++j) {
    uint4 w0 = *(const uint4*)&lw[j * 8];
    uint4 w1v = *(const uint4*)&lw[j * 8 + 4];
    int t = __popc(a0.x ^ w0.x) + __popc(a0.y ^ w0.y) +
            __popc(a0.z ^ w0.z) + __popc(a0.w ^ w0.w) +
            __popc(a1.x ^ w1v.x) + __popc(a1.y ^ w1v.y) +
            __popc(a1.z ^ w1v.z) + __popc(a1.w ^ w1v.w);
    h2w[j >> 5] |= (uint32_t)(t <= 128) << (j & 31);   // dot = 256-2t >= 0
  }
  uint32_t h3 = 0u;
#pragma unroll 4
  for (int j = 0; j < 32; ++j) {
    uint4 w0 = *(const uint4*)&lw[1024 + j * 4];
    int t = __popc(h2w[0] ^ w0.x) + __popc(h2w[1] ^ w0.y) +
            __popc(h2w[2] ^ w0.z) + __popc(h2w[3] ^ w0.w);
    h3 |= (uint32_t)(t <= 64) << j;                    // dot = 128-2t >= 0
  }
  float* o = out + (size_t)b * 10;
#pragma unroll
  for (int c = 0; c < 10; ++c) {
    int t = __popc(h3 ^ lw[1152 + c]);
    o[c] = (float)(32 - 2 * t);                        // final logits, no step
  }
}

extern "C" void kernel_launch(void* const* d_in, const int* in_sizes, int n_in,
                              void* d_out, int out_size, void* d_ws, size_t ws_size,
                              hipStream_t stream) {
  const float* x  = (const float*)d_in[0];
  const float* w1 = (const float*)d_in[1];
  const float* w2 = (const float*)d_in[2];
  const float* w3 = (const float*)d_in[3];
  const float* w4 = (const float*)d_in[4];
  float* out = (float*)d_out;
  uint8_t* ws = (uint8_t*)d_ws;

  uint32_t* cnt  = (uint32_t*)(ws + CNT_OFF);
  uint32_t* list = (uint32_t*)(ws + LIST_OFF);
  bf16*     s1f  = (bf16*)(ws + S1F_OFF);
  uint32_t* w2p  = (uint32_t*)(ws + W2P_OFF);
  uint32_t* w3p  = (uint32_t*)(ws + W3P_OFF);
  uint32_t* w4p  = (uint32_t*)(ws + W4P_OFF);
  uint32_t* h1p  = (uint32_t*)(ws + H1P_OFF);

  prep_kernel<<<800, 256, 0, stream>>>(w1, w2, w3, w4, s1f, w2p, w3p, w4p, cnt);
  gemm1_kernel<<<1024, 256, 0, stream>>>(x, s1f, (uint8_t*)h1p, cnt, list);
  cleanup_kernel<<<256, 256, 0, stream>>>(x, w1, h1p, cnt, list);
  layer234_kernel<<<B_ROWS / 256, 256, 0, stream>>>(h1p, w2p, w3p, w4p, out);
}